// Round 1
// baseline (146.704 us; speedup 1.0000x reference)
//
#include <hip/hip_runtime.h>

typedef unsigned short u16;
typedef unsigned int   u32;
using short8   = __attribute__((ext_vector_type(8))) short;
using f32x4    = __attribute__((ext_vector_type(4))) float;
using ushort4v = __attribute__((ext_vector_type(4))) unsigned short;

#define CDIM 256
#define LDIM 16384
#define LT   128
#define NT   128   // L tiles per batch
#define NB   8

__device__ __forceinline__ u16 f2bf(float f) {
  u32 u = __float_as_uint(f);
  u = (u + 0x7FFFu + ((u >> 16) & 1u)) >> 16;   // RTNE
  return (u16)u;
}

// ---------------- prep: weight bf16 conversion, wvsum, bilinear upsample ----
__global__ void k_prep(const float* __restrict__ wq_x, const float* __restrict__ wk_x,
                       const float* __restrict__ w_out, const float* __restrict__ wv,
                       const float* __restrict__ y,
                       u16* __restrict__ wqx_bf, u16* __restrict__ wkx_bf,
                       u16* __restrict__ wout_bf, u16* __restrict__ wvsum_bf,
                       float* __restrict__ yup) {
  int id = blockIdx.x * 256 + threadIdx.x;
  if (id < 65536) {
    wqx_bf[id]  = f2bf(wq_x[id]);
    wkx_bf[id]  = f2bf(wk_x[id]);
    wout_bf[id] = f2bf(w_out[id]);
  }
  if (id < 4096) {  // wvsum padded to 16 rows (rows 8..15 zero)
    int r = id >> 8, c = id & 255;
    float s = 0.f;
    if (r < 8) {
      for (int d2 = 0; d2 < 32; ++d2) s += wv[(r * 32 + d2) * 256 + c];
    }
    wvsum_bf[id] = f2bf(s);
  }
  if (id < 131072) {  // bilinear 2x upsample, half-pixel (align_corners=False)
    int b = id >> 14, rem = id & 16383, i = rem >> 7, j = rem & 127;
    float si = 0.5f * i - 0.25f, sj = 0.5f * j - 0.25f;
    int i0 = (int)floorf(si), j0 = (int)floorf(sj);
    float fi = si - (float)i0, fj = sj - (float)j0;
    int i0c = i0 < 0 ? 0 : i0, i1c = i0 + 1 > 63 ? 63 : i0 + 1;
    int j0c = j0 < 0 ? 0 : j0, j1c = j0 + 1 > 63 ? 63 : j0 + 1;
    const float* yb = y + b * 4096;
    float v = (1.f - fi) * ((1.f - fj) * yb[i0c * 64 + j0c] + fj * yb[i0c * 64 + j1c])
            +        fi  * ((1.f - fj) * yb[i1c * 64 + j0c] + fj * yb[i1c * 64 + j1c]);
    yup[id] = v;
  }
}

// ---------------- shared staging: x f32 -> LDS bf16 transposed [l][c] -------
// x_lds viewed as u16[128][264] (row stride 264 shorts = 528 B, +8 pad)
__device__ __forceinline__ void stage_x(u32* x_lds, const float* __restrict__ x,
                                        int b, int l0, int tid) {
  int cp = tid & 127, half = tid >> 7;           // channels 2cp,2cp+1 ; l half
  const float4* r0 = (const float4*)(x + ((size_t)(b * 256 + 2 * cp)) * LDIM + l0 + half * 64);
  const float4* r1 = (const float4*)((const float*)r0 + LDIM);
#pragma unroll 4
  for (int j4 = 0; j4 < 16; ++j4) {
    float4 v0 = r0[j4], v1 = r1[j4];
    int lb = half * 64 + j4 * 4;
    x_lds[(lb + 0) * 132 + cp] = (u32)f2bf(v0.x) | ((u32)f2bf(v1.x) << 16);
    x_lds[(lb + 1) * 132 + cp] = (u32)f2bf(v0.y) | ((u32)f2bf(v1.y) << 16);
    x_lds[(lb + 2) * 132 + cp] = (u32)f2bf(v0.z) | ((u32)f2bf(v1.z) << 16);
    x_lds[(lb + 3) * 132 + cp] = (u32)f2bf(v0.w) | ((u32)f2bf(v1.w) << 16);
  }
}

// ---------------- pass 1: ksum / kvs partials --------------------------------
__global__ __launch_bounds__(256, 2) void k_pass1(
    const float* __restrict__ x, const u16* __restrict__ wkx_bf,
    const u16* __restrict__ wvsum_bf, const float* __restrict__ wk_y,
    const float* __restrict__ yup, float* __restrict__ part) {
  __shared__ u32 x_lds[128 * 132];
  __shared__ float vsum_lds[8 * 128];
  __shared__ float yup_lds[128];
  __shared__ float wky_lds[256];

  int tid = threadIdx.x, bid = blockIdx.x;
  int b = bid >> 7, tile = bid & 127;
  int l0 = tile * LT;

  if (tid < 128) yup_lds[tid] = yup[b * LDIM + l0 + tid];
  wky_lds[tid] = wk_y[tid];
  stage_x(x_lds, x, b, l0, tid);
  __syncthreads();

  int lane = tid & 63, wave = tid >> 6;
  int lid = lane & 15, g = lane >> 4;
  int wb = wave * 64;
  const u16* xl = (const u16*)x_lds;

  f32x4 z4 = {0.f, 0.f, 0.f, 0.f};
  f32x4 acc[4][8];
#pragma unroll
  for (int i = 0; i < 4; ++i)
#pragma unroll
    for (int j = 0; j < 8; ++j) acc[i][j] = z4;
  f32x4 vacc[2] = {z4, z4};

  for (int kk = 0; kk < 8; ++kk) {
    int kof = kk * 32 + g * 8;
    short8 a[4];
#pragma unroll
    for (int fm = 0; fm < 4; ++fm)
      a[fm] = *(const short8*)(wkx_bf + (size_t)(wb + fm * 16 + lid) * 256 + kof);
    short8 av = *(const short8*)(wvsum_bf + (size_t)lid * 256 + kof);
#pragma unroll
    for (int fn = 0; fn < 8; ++fn) {
      short8 bb = *(const short8*)(xl + (fn * 16 + lid) * 264 + kof);
#pragma unroll
      for (int fm = 0; fm < 4; ++fm)
        acc[fm][fn] = __builtin_amdgcn_mfma_f32_16x16x32_bf16(a[fm], bb, acc[fm][fn], 0, 0, 0);
    }
    // vsum mini-GEMM: this wave covers fn = 2*wave, 2*wave+1
#pragma unroll
    for (int fv = 0; fv < 2; ++fv) {
      int fn = wave * 2 + fv;
      short8 bb = *(const short8*)(xl + (fn * 16 + lid) * 264 + kof);
      vacc[fv] = __builtin_amdgcn_mfma_f32_16x16x32_bf16(av, bb, vacc[fv], 0, 0, 0);
    }
  }
  // scatter vsum rows 0..7 (g<2 holds rows g*4+r)
  if (g < 2) {
#pragma unroll
    for (int fv = 0; fv < 2; ++fv)
#pragma unroll
      for (int r = 0; r < 4; ++r)
        vsum_lds[(g * 4 + r) * 128 + (wave * 2 + fv) * 16 + lid] = vacc[fv][r];
  }
  __syncthreads();

  // elementwise k + row reductions
  float wky_r[4][4];
#pragma unroll
  for (int fm = 0; fm < 4; ++fm)
#pragma unroll
    for (int r = 0; r < 4; ++r) wky_r[fm][r] = wky_lds[wb + fm * 16 + g * 4 + r];

  float s1[4][4], s2[4][4];
#pragma unroll
  for (int fm = 0; fm < 4; ++fm)
#pragma unroll
    for (int r = 0; r < 4; ++r) { s1[fm][r] = 0.f; s2[fm][r] = 0.f; }

#pragma unroll
  for (int fn = 0; fn < 8; ++fn) {
    float yv = yup_lds[fn * 16 + lid];
#pragma unroll
    for (int fm = 0; fm < 4; ++fm) {
      float vs = vsum_lds[(wave * 2 + (fm >> 1)) * 128 + fn * 16 + lid];
#pragma unroll
      for (int r = 0; r < 4; ++r) {
        float v = acc[fm][fn][r] * (wky_r[fm][r] * yv);
        float k = v > 0.f ? v + 1.f : __expf(v);   // elu(v)+1
        s1[fm][r] += k;
        s2[fm][r] += k * vs;
      }
    }
  }
  // reduce across the 16 lanes of each group (cols), lane lid==0 writes
#pragma unroll
  for (int fm = 0; fm < 4; ++fm)
#pragma unroll
    for (int r = 0; r < 4; ++r) {
      float a1 = s1[fm][r], a2 = s2[fm][r];
#pragma unroll
      for (int off = 1; off < 16; off <<= 1) {
        a1 += __shfl_xor(a1, off);
        a2 += __shfl_xor(a2, off);
      }
      if (lid == 0) {
        int c = wb + fm * 16 + g * 4 + r;
        part[(size_t)bid * 512 + c]       = a1;
        part[(size_t)bid * 512 + 256 + c] = a2;
      }
    }
}

// ---------------- reduce partials -> ksum, kvs -------------------------------
__global__ void k_reduce(const float* __restrict__ part,
                         float* __restrict__ ksum, float* __restrict__ kvs) {
  int b = blockIdx.x, c = threadIdx.x;
  float s1 = 0.f, s2 = 0.f;
  for (int t = 0; t < NT; ++t) {
    s1 += part[(size_t)(b * NT + t) * 512 + c];
    s2 += part[(size_t)(b * NT + t) * 512 + 256 + c];
  }
  ksum[b * 256 + c] = s1;
  kvs[b * 256 + c] = s2;
}

// ---------------- pass 2: q, z, t, w_out GEMM, output ------------------------
__global__ __launch_bounds__(256, 2) void k_pass2(
    const float* __restrict__ x, const u16* __restrict__ wqx_bf,
    const u16* __restrict__ wout_bf, const float* __restrict__ wq_y,
    const float* __restrict__ yup, const float* __restrict__ ksum,
    const float* __restrict__ kvs, const float* __restrict__ b_out,
    float* __restrict__ out) {
  __shared__ u32 x_lds[128 * 132];
  __shared__ float yup_lds[128];
  __shared__ float wqy_lds[256];
  __shared__ float ksum_lds[256];
  __shared__ float kvs_lds[256];
  __shared__ float bout_lds[256];

  int tid = threadIdx.x, bid = blockIdx.x;
  int b = bid >> 7, tile = bid & 127;
  int l0 = tile * LT;

  if (tid < 128) yup_lds[tid] = yup[b * LDIM + l0 + tid];
  wqy_lds[tid]  = wq_y[tid];
  ksum_lds[tid] = ksum[b * 256 + tid];
  kvs_lds[tid]  = kvs[b * 256 + tid];
  bout_lds[tid] = b_out[tid];
  stage_x(x_lds, x, b, l0, tid);
  __syncthreads();

  int lane = tid & 63, wave = tid >> 6;
  int lid = lane & 15, g = lane >> 4;
  int wb = wave * 64;
  u16* xl = (u16*)x_lds;

  f32x4 z4 = {0.f, 0.f, 0.f, 0.f};
  f32x4 acc[4][8];
#pragma unroll
  for (int i = 0; i < 4; ++i)
#pragma unroll
    for (int j = 0; j < 8; ++j) acc[i][j] = z4;

  // GEMM1: q_x = wq_x * x
  for (int kk = 0; kk < 8; ++kk) {
    int kof = kk * 32 + g * 8;
    short8 a[4];
#pragma unroll
    for (int fm = 0; fm < 4; ++fm)
      a[fm] = *(const short8*)(wqx_bf + (size_t)(wb + fm * 16 + lid) * 256 + kof);
#pragma unroll
    for (int fn = 0; fn < 8; ++fn) {
      short8 bb = *(const short8*)((const u16*)xl + (fn * 16 + lid) * 264 + kof);
#pragma unroll
      for (int fm = 0; fm < 4; ++fm)
        acc[fm][fn] = __builtin_amdgcn_mfma_f32_16x16x32_bf16(a[fm], bb, acc[fm][fn], 0, 0, 0);
    }
  }
  __syncthreads();  // all x_lds reads done; buffer is reused for t

  float wqy_r[4][4], ks_r[4][4], kv_r[4][4];
#pragma unroll
  for (int fm = 0; fm < 4; ++fm)
#pragma unroll
    for (int r = 0; r < 4; ++r) {
      int c = wb + fm * 16 + g * 4 + r;
      wqy_r[fm][r] = wqy_lds[c];
      ks_r[fm][r]  = ksum_lds[c];
      kv_r[fm][r]  = kvs_lds[c];
    }

#pragma unroll
  for (int fn = 0; fn < 8; ++fn) {
    float yv = yup_lds[fn * 16 + lid];
    float q[4][4];
    float d0 = 0.f, d1 = 0.f;
#pragma unroll
    for (int fm = 0; fm < 4; ++fm)
#pragma unroll
      for (int r = 0; r < 4; ++r) {
        float v = acc[fm][fn][r] * (wqy_r[fm][r] * yv);
        float qq = v > 0.f ? v + 1.f : __expf(v);   // elu(v)+1
        q[fm][r] = qq;
        if (fm < 2) d0 += qq * ks_r[fm][r]; else d1 += qq * ks_r[fm][r];
      }
    d0 += __shfl_xor(d0, 16); d0 += __shfl_xor(d0, 32);
    d1 += __shfl_xor(d1, 16); d1 += __shfl_xor(d1, 32);
    float zz0 = 1.f / (d0 + 1e-6f), zz1 = 1.f / (d1 + 1e-6f);
    int l = fn * 16 + lid;
#pragma unroll
    for (int fm = 0; fm < 4; ++fm) {
      float zz = fm < 2 ? zz0 : zz1;
      ushort4v tw;
#pragma unroll
      for (int r = 0; r < 4; ++r) tw[r] = f2bf(q[fm][r] * kv_r[fm][r] * zz);
      *(ushort4v*)((u16*)xl + l * 264 + wb + fm * 16 + g * 4) = tw;
    }
  }
  __syncthreads();

  // GEMM2: out = w_out * t
#pragma unroll
  for (int i = 0; i < 4; ++i)
#pragma unroll
    for (int j = 0; j < 8; ++j) acc[i][j] = z4;
  for (int kk = 0; kk < 8; ++kk) {
    int kof = kk * 32 + g * 8;
    short8 a[4];
#pragma unroll
    for (int fm = 0; fm < 4; ++fm)
      a[fm] = *(const short8*)(wout_bf + (size_t)(wb + fm * 16 + lid) * 256 + kof);
#pragma unroll
    for (int fn = 0; fn < 8; ++fn) {
      short8 bb = *(const short8*)((const u16*)xl + (fn * 16 + lid) * 264 + kof);
#pragma unroll
      for (int fm = 0; fm < 4; ++fm)
        acc[fm][fn] = __builtin_amdgcn_mfma_f32_16x16x32_bf16(a[fm], bb, acc[fm][fn], 0, 0, 0);
    }
  }

  // epilogue
#pragma unroll
  for (int fm = 0; fm < 4; ++fm) {
#pragma unroll
    for (int r = 0; r < 4; ++r) {
      int o = wb + fm * 16 + g * 4 + r;
      float bo = bout_lds[o];
      size_t base = ((size_t)b * 256 + o) * LDIM + l0;
#pragma unroll
      for (int fn = 0; fn < 8; ++fn)
        out[base + fn * 16 + lid] = acc[fm][fn][r] + bo;
    }
  }
}

// ---------------- launch ------------------------------------------------------
extern "C" void kernel_launch(void* const* d_in, const int* in_sizes, int n_in,
                              void* d_out, int out_size, void* d_ws, size_t ws_size,
                              hipStream_t stream) {
  const float* x     = (const float*)d_in[0];
  const float* y     = (const float*)d_in[1];
  const float* wq_x  = (const float*)d_in[2];
  const float* wk_x  = (const float*)d_in[3];
  const float* wv    = (const float*)d_in[4];
  const float* wq_y  = (const float*)d_in[5];
  const float* wk_y  = (const float*)d_in[6];
  const float* w_out = (const float*)d_in[7];
  const float* b_out = (const float*)d_in[8];
  float* out = (float*)d_out;

  char* ws = (char*)d_ws;
  float* yup      = (float*)(ws + 0);        // 131072 f32 = 512 KB
  u16*   wqx_bf   = (u16*)(ws + 524288);     // 128 KB
  u16*   wkx_bf   = (u16*)(ws + 655360);     // 128 KB
  u16*   wout_bf  = (u16*)(ws + 786432);     // 128 KB
  u16*   wvsum_bf = (u16*)(ws + 917504);     // 16x256 u16 = 8 KB
  float* ksum     = (float*)(ws + 925696);   // 8 KB
  float* kvs      = (float*)(ws + 933888);   // 8 KB
  float* part     = (float*)(ws + 942080);   // 8*128*512 f32 = 2 MB

  k_prep<<<512, 256, 0, stream>>>(wq_x, wk_x, w_out, wv, y,
                                  wqx_bf, wkx_bf, wout_bf, wvsum_bf, yup);
  k_pass1<<<NB * NT, 256, 0, stream>>>(x, wkx_bf, wvsum_bf, wk_y, yup, part);
  k_reduce<<<NB, 256, 0, stream>>>(part, ksum, kvs);
  k_pass2<<<NB * NT, 256, 0, stream>>>(x, wqx_bf, wout_bf, wq_y, yup,
                                       ksum, kvs, b_out, out);
}